// Round 3
// baseline (535.143 us; speedup 1.0000x reference)
//
#include <hip/hip_runtime.h>
#include <math.h>

#define BB 128
#define CIN 512
#define HW 64
#define OUTC 256
#define EMB 4096
#define DDIM 4096
#define ES 32
#define QCH 32          // D-chunks in k_main (128 d each)

// workspace layout (float offsets)
#define ENC_OFF   0          // 8192 ints
#define TSUM_OFF  8192       // 4096
#define TLOGT_OFF 12288      // 4096
#define PL_OFF    16384      // 128*32*64 = 262144
#define PD_OFF    278528     // 128*32 = 4096
#define CNT_OFF   282624     // 128 ints

typedef short short8 __attribute__((ext_vector_type(8)));
typedef float floatx4 __attribute__((ext_vector_type(4)));

__device__ __forceinline__ unsigned short f2bf(float f) {
    unsigned int u = __builtin_bit_cast(unsigned int, f);
    u += 0x7FFFu + ((u >> 16) & 1u);          // RNE; inputs are finite
    return (unsigned short)(u >> 16);
}

// ---------------- K1: LDA (blocks 0..511)  ||  rowsum (blocks 512..4607) ----
// R2 post-mortem: LDS-resident mega-fusion (1 block/b, 106KB LDS) regressed
// 17us — occupancy + overlap beat fusion here. This is the proven R1 split:
// lda 512 blocks (5KB LDS, many/CU) overlapped with 4096 rowsum blocks.
__global__ __launch_bounds__(256) void k_pre(const float* __restrict__ feat,
                                             const float* __restrict__ w,
                                             const float* __restrict__ bias,
                                             float* __restrict__ ft,
                                             float* __restrict__ out,
                                             const float* __restrict__ ts,
                                             const int* __restrict__ labels,
                                             float* __restrict__ tsum,
                                             float* __restrict__ tlogt,
                                             int* __restrict__ cnt) {
    __shared__ unsigned short As[64 * 40];    // lda staging, row stride 40
    __shared__ int present;
    __shared__ float r[8];
    int bx = blockIdx.x;
    int tid = threadIdx.x;
    if (bx >= 512) {
        // ---------------- rowsum role ----------------
        int e = bx - 512;
        if (tid == 0) present = 0;
        __syncthreads();
        int cls = e >> 5;
        if (tid < BB && labels[tid] == cls) present = 1;
        __syncthreads();
        if (!present) return;
        const float* row = ts + (size_t)e * DDIM;
        float st_ = 0.f, sl = 0.f;
#pragma unroll
        for (int i = 0; i < 4; ++i) {
            float4 t4 = *(const float4*)&row[tid * 4 + i * 1024];
            float tv[4] = {t4.x, t4.y, t4.z, t4.w};
#pragma unroll
            for (int j = 0; j < 4; ++j) {
                float t = tv[j];
                st_ += t;
                sl += (t > 0.f) ? t * logf(t) : 0.f;
            }
        }
        for (int off = 32; off; off >>= 1) {
            st_ += __shfl_down(st_, off);
            sl += __shfl_down(sl, off);
        }
        int lane = tid & 63, wv = tid >> 6;
        if (lane == 0) { r[wv] = st_; r[4 + wv] = sl; }
        __syncthreads();
        if (tid == 0) {
            tsum[e]  = r[0] + r[1] + r[2] + r[3];
            tlogt[e] = r[4] + r[5] + r[6] + r[7];
        }
        return;
    }
    // ---------------- LDA role ----------------
    if (bx == 0) {
        if (tid == 0) *out = 0.f;             // zero loss accumulator
        if (tid < BB) cnt[tid] = 0;           // zero completion counters
    }
    int nb = bx >> 2, ob = bx & 3;
    int n0 = nb * 64, o0 = ob * 64;
    int lane = tid & 63, wid = tid >> 6;
    int m = lane & 15, q = lane >> 4;
    int cc = tid >> 4;                        // staging: channels c and c+16
    int p4 = (tid & 15) * 4;                  // staging: 4 consecutive pixels
    const float* fbase = feat + (size_t)nb * CIN * HW;
    const float* wrow  = w + (size_t)(o0 + wid * 16 + m) * CIN;
    floatx4 acc[4] = {};
    for (int kt = 0; kt < 16; ++kt) {
        int k0 = kt * 32;
        float4 v0 = *(const float4*)(fbase + (size_t)(k0 + cc) * HW + p4);
        float4 v1 = *(const float4*)(fbase + (size_t)(k0 + cc + 16) * HW + p4);
        float4 w0 = *(const float4*)(wrow + k0 + 4 * q);
        float4 w1 = *(const float4*)(wrow + k0 + 16 + 4 * q);
        short8 bf;
        bf[0] = (short)f2bf(w0.x); bf[1] = (short)f2bf(w1.x);
        bf[2] = (short)f2bf(w0.y); bf[3] = (short)f2bf(w1.y);
        bf[4] = (short)f2bf(w0.z); bf[5] = (short)f2bf(w1.z);
        bf[6] = (short)f2bf(w0.w); bf[7] = (short)f2bf(w1.w);
        ushort2 pk;
        pk.x = f2bf(v0.x); pk.y = f2bf(v1.x);
        *(ushort2*)&As[(p4 + 0) * 40 + 2 * cc] = pk;
        pk.x = f2bf(v0.y); pk.y = f2bf(v1.y);
        *(ushort2*)&As[(p4 + 1) * 40 + 2 * cc] = pk;
        pk.x = f2bf(v0.z); pk.y = f2bf(v1.z);
        *(ushort2*)&As[(p4 + 2) * 40 + 2 * cc] = pk;
        pk.x = f2bf(v0.w); pk.y = f2bf(v1.w);
        *(ushort2*)&As[(p4 + 3) * 40 + 2 * cc] = pk;
        __syncthreads();
#pragma unroll
        for (int mt = 0; mt < 4; ++mt) {
            short8 af = *(short8*)&As[(mt * 16 + m) * 40 + q * 8];
            acc[mt] = __builtin_amdgcn_mfma_f32_16x16x32_bf16(af, bf, acc[mt], 0, 0, 0);
        }
        __syncthreads();
    }
    float bv = bias[o0 + wid * 16 + m];
#pragma unroll
    for (int mt = 0; mt < 4; ++mt)
#pragma unroll
        for (int rr = 0; rr < 4; ++rr) {
            int p = mt * 16 + q * 4 + rr;     // C/D: row = quad*4+reg, col = lane&15
            ft[(size_t)(n0 + p) * OUTC + o0 + wid * 16 + m] = acc[mt][rr] + bv;
        }
}

// ---------------- K2: enc = cls*32 + argmin_j ||ft_n - c_j||^2 --------------
// 256 blocks (b, pixel-half); centers async-staged via global_load_lds
// (wave-uniform LDS dest + lane*16B, verified pattern) so staging overlaps
// the ft prefetch loads; 8 groups x 4 centers; double-buffered x row.
__global__ __launch_bounds__(256) void k_enc(const float* __restrict__ ft,
                                             const float* __restrict__ cc,
                                             const int* __restrict__ labels,
                                             int* __restrict__ enc) {
    __shared__ __align__(16) float cbuf[ES * OUTC];   // 32 KB
    __shared__ float vred[8 * 32];
    __shared__ int   ired[8 * 32];
    int bx = blockIdx.x;
    int b = bx >> 1, ph = bx & 1;
    int tid = threadIdx.x;
    int lane = tid & 63, wid = tid >> 6;
    int cls = labels[b];
    const float* cbase = cc + (size_t)cls * ES * OUTC;
#pragma unroll
    for (int it = 0; it < 8; ++it) {
        int ch = wid * 8 + it;                // wave-uniform row; HW adds lane*16B
        __builtin_amdgcn_global_load_lds(
            (const __attribute__((address_space(1))) void*)(cbase + ch * OUTC + lane * 4),
            (__attribute__((address_space(3))) void*)&cbuf[ch * OUTC],
            16, 0, 0);
    }
    int p = tid & 31, jg = tid >> 5;          // 8 groups x 4 centers
    const float* xrow = ft + (size_t)(b * 64 + ph * 32 + p) * OUTC;
    float4 xa = *(const float4*)&xrow[0];
    float4 xb = *(const float4*)&xrow[4];
    float4 xc = *(const float4*)&xrow[8];
    float4 xd = *(const float4*)&xrow[12];
    __syncthreads();                          // drains global_load_lds (vmcnt)
    float sc[4] = {0.f, 0.f, 0.f, 0.f};
    for (int o = 0; o < OUTC; o += 16) {
        int on = (o + 16) & (OUTC - 1);       // wrap: last prefetch harmless
        float4 na = *(const float4*)&xrow[on + 0];
        float4 nb = *(const float4*)&xrow[on + 4];
        float4 nc = *(const float4*)&xrow[on + 8];
        float4 nd = *(const float4*)&xrow[on + 12];
        float ma0 = -2.f * xa.x, ma1 = -2.f * xa.y, ma2 = -2.f * xa.z, ma3 = -2.f * xa.w;
        float mb0 = -2.f * xb.x, mb1 = -2.f * xb.y, mb2 = -2.f * xb.z, mb3 = -2.f * xb.w;
        float mc0 = -2.f * xc.x, mc1 = -2.f * xc.y, mc2 = -2.f * xc.z, mc3 = -2.f * xc.w;
        float md0 = -2.f * xd.x, md1 = -2.f * xd.y, md2 = -2.f * xd.z, md3 = -2.f * xd.w;
#pragma unroll
        for (int jj = 0; jj < 4; ++jj) {
            const float* crow = &cbuf[(jg * 4 + jj) * OUTC + o];
            float4 c0 = *(const float4*)&crow[0];
            float4 c1 = *(const float4*)&crow[4];
            float4 c2 = *(const float4*)&crow[8];
            float4 c3 = *(const float4*)&crow[12];
            float s = sc[jj];
            s = fmaf(c0.x, c0.x + ma0, s);
            s = fmaf(c0.y, c0.y + ma1, s);
            s = fmaf(c0.z, c0.z + ma2, s);
            s = fmaf(c0.w, c0.w + ma3, s);
            s = fmaf(c1.x, c1.x + mb0, s);
            s = fmaf(c1.y, c1.y + mb1, s);
            s = fmaf(c1.z, c1.z + mb2, s);
            s = fmaf(c1.w, c1.w + mb3, s);
            s = fmaf(c2.x, c2.x + mc0, s);
            s = fmaf(c2.y, c2.y + mc1, s);
            s = fmaf(c2.z, c2.z + mc2, s);
            s = fmaf(c2.w, c2.w + mc3, s);
            s = fmaf(c3.x, c3.x + md0, s);
            s = fmaf(c3.y, c3.y + md1, s);
            s = fmaf(c3.z, c3.z + md2, s);
            s = fmaf(c3.w, c3.w + md3, s);
            sc[jj] = s;
        }
        xa = na; xb = nb; xc = nc; xd = nd;
    }
    float best = sc[0]; int bj = jg * 4;
#pragma unroll
    for (int jj = 1; jj < 4; ++jj)
        if (sc[jj] < best) { best = sc[jj]; bj = jg * 4 + jj; }
    vred[jg * 32 + p] = best;
    ired[jg * 32 + p] = bj;
    __syncthreads();
    if (tid < 32) {
        float bv = vred[tid]; int bi = ired[tid];
#pragma unroll
        for (int g = 1; g < 8; ++g) {
            float v = vred[g * 32 + tid];
            if (v < bv) { bv = v; bi = ired[g * 32 + tid]; }
        }
        enc[b * 64 + ph * 32 + tid] = cls * ES + bi;
    }
}

// ---------------- K3: sumexp + block-scalar dot + last-block merge ----------
// Per-(b,q): phase 1 streams scores coalesced (stages tile transposed in LDS),
// phase 2 computes the block-scalar dot with ts rows read coalesced.
// The last block per b (completion counter, device-scope atomics+fences)
// performs the former k_final merge — one fewer launch.
__global__ __launch_bounds__(256) void k_main(const float* __restrict__ scores,
                                              const float* __restrict__ ts,
                                              const int* __restrict__ enc,
                                              float* __restrict__ pl,
                                              float* __restrict__ pd,
                                              const float* __restrict__ tsum,
                                              const float* __restrict__ tlogt,
                                              int* __restrict__ cnt,
                                              float* __restrict__ out) {
    __shared__ float st[128 * 65];            // [d][p], pad 65
    __shared__ float redl[4 * 64];
    __shared__ int   etab[64];
    __shared__ float rd[4];
    __shared__ int   lastf;
    int bx = blockIdx.x;
    int b = bx >> 5, q = bx & 31;
    int tid = threadIdx.x;
    int lane = tid & 63, wv = tid >> 6;
    int pg = lane & 15, lg = lane >> 4;
    if (tid < 64) etab[tid] = enc[b * 64 + tid] * DDIM;
    int p4 = pg * 4;
    int dl = wv * 4 + lg;                     // local d in [0,16), +16*it
    const float* sptr = scores + (size_t)b * DDIM * HW + (size_t)(q * 128 + dl) * HW + p4;
    float l0 = 0.f, l1 = 0.f, l2 = 0.f, l3 = 0.f;
#pragma unroll
    for (int it = 0; it < 8; ++it) {
        float4 s4 = *(const float4*)(sptr + (size_t)(it * 16) * HW);
        float* sw = &st[(dl + it * 16) * 65 + p4];    // banks (d+p)%32: free
        sw[0] = s4.x; sw[1] = s4.y; sw[2] = s4.z; sw[3] = s4.w;
        l0 += __expf(s4.x);
        l1 += __expf(s4.y);
        l2 += __expf(s4.z);
        l3 += __expf(s4.w);
    }
    l0 += __shfl_xor(l0, 16); l0 += __shfl_xor(l0, 32);
    l1 += __shfl_xor(l1, 16); l1 += __shfl_xor(l1, 32);
    l2 += __shfl_xor(l2, 16); l2 += __shfl_xor(l2, 32);
    l3 += __shfl_xor(l3, 16); l3 += __shfl_xor(l3, 32);
    if (lg == 0) {
        redl[wv * 64 + p4 + 0] = l0;
        redl[wv * 64 + p4 + 1] = l1;
        redl[wv * 64 + p4 + 2] = l2;
        redl[wv * 64 + p4 + 3] = l3;
    }
    __syncthreads();
    if (tid < 64) {
        float L = redl[tid] + redl[64 + tid] + redl[128 + tid] + redl[192 + tid];
        pl[(b * QCH + q) * 64 + tid] = L;
    }
    // ---- phase 2: D_block = sum_{p,d in chunk} st[d][p] * ts[e_p][d]
    int d = tid & 127, ph2 = tid >> 7;        // 2 threads per d, split p-range
    const float* tsq = ts + (size_t)q * 128 + d;
    float D = 0.f;
#pragma unroll 8
    for (int i = 0; i < 32; ++i) {
        int p = ph2 * 32 + i;                 // wave-uniform p
        float sv = st[d * 65 + p];            // banks (d+p)%32: 2-way, free
        float tv = tsq[etab[p]];              // lanes span d: 256B coalesced
        D = fmaf(sv, tv, D);
    }
#pragma unroll
    for (int off = 1; off < 64; off <<= 1) D += __shfl_xor(D, off);
    if (lane == 0) rd[wv] = D;
    __syncthreads();
    if (tid == 0) pd[b * QCH + q] = rd[0] + rd[1] + rd[2] + rd[3];
    // ---- completion-counter merge (replaces k_final)
    if (tid == 0) {
        __threadfence();                      // release pl/pd writes
        lastf = (atomicAdd(&cnt[b], 1) == QCH - 1);
    }
    __syncthreads();
    if (!lastf) return;
    __threadfence();                          // acquire other blocks' writes
    if (tid < 64) {
        int p = tid;
        float L = 0.f;
#pragma unroll
        for (int qq = 0; qq < QCH; ++qq) L += pl[(b * QCH + qq) * 64 + p];
        float lse = logf(L);
        int e = enc[b * 64 + p];
        float row = tlogt[e] + tsum[e] * lse;
        if (p < QCH) row -= pd[b * QCH + p];  // sum_p of these = D_batch
        for (int off = 32; off; off >>= 1) row += __shfl_down(row, off);
        if (p == 0) atomicAdd(out, row * (1.f / 8192.f));
    }
}

extern "C" void kernel_launch(void* const* d_in, const int* in_sizes, int n_in,
                              void* d_out, int out_size, void* d_ws, size_t ws_size,
                              hipStream_t stream) {
    const float* feat   = (const float*)d_in[0];
    const float* scores = (const float*)d_in[1];
    const int*   labels = (const int*)d_in[2];
    const float* ldaw   = (const float*)d_in[3];
    const float* ldab   = (const float*)d_in[4];
    const float* cc     = (const float*)d_in[5];
    const float* ts     = (const float*)d_in[6];
    float* out = (float*)d_out;
    float* ws  = (float*)d_ws;

    float* ft    = ws + 1048576;              // 8192*256 floats, after low block
    int*   enc   = (int*)(ws + ENC_OFF);
    float* tsum  = ws + TSUM_OFF;
    float* tlogt = ws + TLOGT_OFF;
    float* pl    = ws + PL_OFF;
    float* pd    = ws + PD_OFF;
    int*   cnt   = (int*)(ws + CNT_OFF);

    k_pre  <<<512 + EMB, 256, 0, stream>>>(feat, ldaw, ldab, ft, out, ts, labels, tsum, tlogt, cnt);
    k_enc  <<<BB * 2,    256, 0, stream>>>(ft, cc, labels, enc);
    k_main <<<BB * QCH,  256, 0, stream>>>(scores, ts, enc, pl, pd, tsum, tlogt, cnt, out);
}

// Round 4
// 282.499 us; speedup vs baseline: 1.8943x; 1.8943x over previous
//
#include <hip/hip_runtime.h>
#include <math.h>

#define BB 128
#define CIN 512
#define HW 64
#define OUTC 256
#define EMB 4096
#define DDIM 4096
#define ES 32
#define QCH 32          // D-chunks in k_main (128 d each)

// workspace layout (float offsets)
#define ENC_OFF   0          // 8192 ints
#define TSUM_OFF  8192       // 4096
#define TLOGT_OFF 12288      // 4096
#define PL_OFF    16384      // 128*32*64 = 262144
#define PD_OFF    278528     // 128*32 = 4096
#define FT_OFF    1048576    // 8192*256 floats

typedef short short8 __attribute__((ext_vector_type(8)));
typedef float floatx4 __attribute__((ext_vector_type(4)));

__device__ __forceinline__ unsigned short f2bf(float f) {
    unsigned int u = __builtin_bit_cast(unsigned int, f);
    u += 0x7FFFu + ((u >> 16) & 1u);          // RNE; inputs are finite
    return (unsigned short)(u >> 16);
}

// ---------------- K1: pure LDA, 512 blocks (~7us) ---------------------------
// R3 post-mortem: NO device fences / cross-block merges — 4096 per-block L2
// flush-fences serialized k_main to 350us. Dependent reductions stay in their
// own launches. rowsum moved off the critical path into k_main's grid.
__global__ __launch_bounds__(256) void k_lda(const float* __restrict__ feat,
                                             const float* __restrict__ w,
                                             const float* __restrict__ bias,
                                             float* __restrict__ ft,
                                             float* __restrict__ out) {
    __shared__ unsigned short As[64 * 40];    // staging, row stride 40
    int bx = blockIdx.x;
    int tid = threadIdx.x;
    if (bx == 0 && tid == 0) *out = 0.f;      // zero loss accumulator
    int nb = bx >> 2, ob = bx & 3;
    int n0 = nb * 64, o0 = ob * 64;
    int lane = tid & 63, wid = tid >> 6;
    int m = lane & 15, q = lane >> 4;
    int cc = tid >> 4;                        // staging: channels c and c+16
    int p4 = (tid & 15) * 4;                  // staging: 4 consecutive pixels
    const float* fbase = feat + (size_t)nb * CIN * HW;
    const float* wrow  = w + (size_t)(o0 + wid * 16 + m) * CIN;
    floatx4 acc[4] = {};
    for (int kt = 0; kt < 16; ++kt) {
        int k0 = kt * 32;
        float4 v0 = *(const float4*)(fbase + (size_t)(k0 + cc) * HW + p4);
        float4 v1 = *(const float4*)(fbase + (size_t)(k0 + cc + 16) * HW + p4);
        float4 w0 = *(const float4*)(wrow + k0 + 4 * q);
        float4 w1 = *(const float4*)(wrow + k0 + 16 + 4 * q);
        short8 bf;
        bf[0] = (short)f2bf(w0.x); bf[1] = (short)f2bf(w1.x);
        bf[2] = (short)f2bf(w0.y); bf[3] = (short)f2bf(w1.y);
        bf[4] = (short)f2bf(w0.z); bf[5] = (short)f2bf(w1.z);
        bf[6] = (short)f2bf(w0.w); bf[7] = (short)f2bf(w1.w);
        ushort2 pk;
        pk.x = f2bf(v0.x); pk.y = f2bf(v1.x);
        *(ushort2*)&As[(p4 + 0) * 40 + 2 * cc] = pk;
        pk.x = f2bf(v0.y); pk.y = f2bf(v1.y);
        *(ushort2*)&As[(p4 + 1) * 40 + 2 * cc] = pk;
        pk.x = f2bf(v0.z); pk.y = f2bf(v1.z);
        *(ushort2*)&As[(p4 + 2) * 40 + 2 * cc] = pk;
        pk.x = f2bf(v0.w); pk.y = f2bf(v1.w);
        *(ushort2*)&As[(p4 + 3) * 40 + 2 * cc] = pk;
        __syncthreads();
#pragma unroll
        for (int mt = 0; mt < 4; ++mt) {
            short8 af = *(short8*)&As[(mt * 16 + m) * 40 + q * 8];
            acc[mt] = __builtin_amdgcn_mfma_f32_16x16x32_bf16(af, bf, acc[mt], 0, 0, 0);
        }
        __syncthreads();
    }
    float bv = bias[o0 + wid * 16 + m];
#pragma unroll
    for (int mt = 0; mt < 4; ++mt)
#pragma unroll
        for (int rr = 0; rr < 4; ++rr) {
            int p = mt * 16 + q * 4 + rr;     // C/D: row = quad*4+reg, col = lane&15
            ft[(size_t)(n0 + p) * OUTC + o0 + wid * 16 + m] = acc[mt][rr] + bv;
        }
}

// ---------------- K2: enc = cls*32 + argmin_j ||ft_n - c_j||^2 --------------
// 256 blocks (b, pixel-half); centers async-staged via global_load_lds
// (verified correct in R3); 8 groups x 4 centers; double-buffered x row.
__global__ __launch_bounds__(256) void k_enc(const float* __restrict__ ft,
                                             const float* __restrict__ cc,
                                             const int* __restrict__ labels,
                                             int* __restrict__ enc) {
    __shared__ __align__(16) float cbuf[ES * OUTC];   // 32 KB
    __shared__ float vred[8 * 32];
    __shared__ int   ired[8 * 32];
    int bx = blockIdx.x;
    int b = bx >> 1, ph = bx & 1;
    int tid = threadIdx.x;
    int lane = tid & 63, wid = tid >> 6;
    int cls = labels[b];
    const float* cbase = cc + (size_t)cls * ES * OUTC;
#pragma unroll
    for (int it = 0; it < 8; ++it) {
        int ch = wid * 8 + it;                // wave-uniform row; HW adds lane*16B
        __builtin_amdgcn_global_load_lds(
            (const __attribute__((address_space(1))) void*)(cbase + ch * OUTC + lane * 4),
            (__attribute__((address_space(3))) void*)&cbuf[ch * OUTC],
            16, 0, 0);
    }
    int p = tid & 31, jg = tid >> 5;          // 8 groups x 4 centers
    const float* xrow = ft + (size_t)(b * 64 + ph * 32 + p) * OUTC;
    float4 xa = *(const float4*)&xrow[0];
    float4 xb = *(const float4*)&xrow[4];
    float4 xc = *(const float4*)&xrow[8];
    float4 xd = *(const float4*)&xrow[12];
    __syncthreads();                          // drains global_load_lds (vmcnt)
    float sc[4] = {0.f, 0.f, 0.f, 0.f};
    for (int o = 0; o < OUTC; o += 16) {
        int on = (o + 16) & (OUTC - 1);       // wrap: last prefetch harmless
        float4 na = *(const float4*)&xrow[on + 0];
        float4 nb = *(const float4*)&xrow[on + 4];
        float4 nc = *(const float4*)&xrow[on + 8];
        float4 nd = *(const float4*)&xrow[on + 12];
        float ma0 = -2.f * xa.x, ma1 = -2.f * xa.y, ma2 = -2.f * xa.z, ma3 = -2.f * xa.w;
        float mb0 = -2.f * xb.x, mb1 = -2.f * xb.y, mb2 = -2.f * xb.z, mb3 = -2.f * xb.w;
        float mc0 = -2.f * xc.x, mc1 = -2.f * xc.y, mc2 = -2.f * xc.z, mc3 = -2.f * xc.w;
        float md0 = -2.f * xd.x, md1 = -2.f * xd.y, md2 = -2.f * xd.z, md3 = -2.f * xd.w;
#pragma unroll
        for (int jj = 0; jj < 4; ++jj) {
            const float* crow = &cbuf[(jg * 4 + jj) * OUTC + o];
            float4 c0 = *(const float4*)&crow[0];
            float4 c1 = *(const float4*)&crow[4];
            float4 c2 = *(const float4*)&crow[8];
            float4 c3 = *(const float4*)&crow[12];
            float s = sc[jj];
            s = fmaf(c0.x, c0.x + ma0, s);
            s = fmaf(c0.y, c0.y + ma1, s);
            s = fmaf(c0.z, c0.z + ma2, s);
            s = fmaf(c0.w, c0.w + ma3, s);
            s = fmaf(c1.x, c1.x + mb0, s);
            s = fmaf(c1.y, c1.y + mb1, s);
            s = fmaf(c1.z, c1.z + mb2, s);
            s = fmaf(c1.w, c1.w + mb3, s);
            s = fmaf(c2.x, c2.x + mc0, s);
            s = fmaf(c2.y, c2.y + mc1, s);
            s = fmaf(c2.z, c2.z + mc2, s);
            s = fmaf(c2.w, c2.w + mc3, s);
            s = fmaf(c3.x, c3.x + md0, s);
            s = fmaf(c3.y, c3.y + md1, s);
            s = fmaf(c3.z, c3.z + md2, s);
            s = fmaf(c3.w, c3.w + md3, s);
            sc[jj] = s;
        }
        xa = na; xb = nb; xc = nc; xd = nd;
    }
    float best = sc[0]; int bj = jg * 4;
#pragma unroll
    for (int jj = 1; jj < 4; ++jj)
        if (sc[jj] < best) { best = sc[jj]; bj = jg * 4 + jj; }
    vred[jg * 32 + p] = best;
    ired[jg * 32 + p] = bj;
    __syncthreads();
    if (tid < 32) {
        float bv = vred[tid]; int bi = ired[tid];
#pragma unroll
        for (int g = 1; g < 8; ++g) {
            float v = vred[g * 32 + tid];
            if (v < bv) { bv = v; bi = ired[g * 32 + tid]; }
        }
        enc[b * 64 + ph * 32 + tid] = cls * ES + bi;
    }
}

// ---------------- K3: main stream (blocks 0..4095)  ||  rowsum (4096..8191) -
// main: per-(b,q) per-pixel sumexp + block-scalar dot (Sum_p D[p] identity).
// rowsum: independent, fused here (verified in R2) so it overlaps the scores
// stream instead of delaying k_enc. No fences — outputs consumed next launch.
__global__ __launch_bounds__(256) void k_main(const float* __restrict__ scores,
                                              const float* __restrict__ ts,
                                              const int* __restrict__ enc,
                                              const int* __restrict__ labels,
                                              float* __restrict__ pl,
                                              float* __restrict__ pd,
                                              float* __restrict__ tsum,
                                              float* __restrict__ tlogt) {
    __shared__ float st[128 * 65];            // [d][p], pad 65
    __shared__ float redl[4 * 64];
    __shared__ int   etab[64];
    __shared__ float rd[4];
    __shared__ int present;
    __shared__ float r8[8];
    int bx = blockIdx.x;
    int tid = threadIdx.x;
    if (bx >= BB * QCH) {
        // ---------------- rowsum role ----------------
        int e = bx - BB * QCH;
        if (tid == 0) present = 0;
        __syncthreads();
        int cls = e >> 5;
        if (tid < BB && labels[tid] == cls) present = 1;
        __syncthreads();
        if (!present) return;
        const float* row = ts + (size_t)e * DDIM;
        float st_ = 0.f, sl = 0.f;
#pragma unroll
        for (int i = 0; i < 4; ++i) {
            float4 t4 = *(const float4*)&row[tid * 4 + i * 1024];
            float tv[4] = {t4.x, t4.y, t4.z, t4.w};
#pragma unroll
            for (int j = 0; j < 4; ++j) {
                float t = tv[j];
                st_ += t;
                sl += (t > 0.f) ? t * logf(t) : 0.f;
            }
        }
        for (int off = 32; off; off >>= 1) {
            st_ += __shfl_down(st_, off);
            sl += __shfl_down(sl, off);
        }
        int lane = tid & 63, wv = tid >> 6;
        if (lane == 0) { r8[wv] = st_; r8[4 + wv] = sl; }
        __syncthreads();
        if (tid == 0) {
            tsum[e]  = r8[0] + r8[1] + r8[2] + r8[3];
            tlogt[e] = r8[4] + r8[5] + r8[6] + r8[7];
        }
        return;
    }
    // ---------------- main role ----------------
    int b = bx >> 5, q = bx & 31;
    int lane = tid & 63, wv = tid >> 6;
    int pg = lane & 15, lg = lane >> 4;
    if (tid < 64) etab[tid] = enc[b * 64 + tid] * DDIM;
    int p4 = pg * 4;
    int dl = wv * 4 + lg;                     // local d in [0,16), +16*it
    const float* sptr = scores + (size_t)b * DDIM * HW + (size_t)(q * 128 + dl) * HW + p4;
    float l0 = 0.f, l1 = 0.f, l2 = 0.f, l3 = 0.f;
#pragma unroll
    for (int it = 0; it < 8; ++it) {
        float4 s4 = *(const float4*)(sptr + (size_t)(it * 16) * HW);
        float* sw = &st[(dl + it * 16) * 65 + p4];    // banks (d+p)%32: free
        sw[0] = s4.x; sw[1] = s4.y; sw[2] = s4.z; sw[3] = s4.w;
        l0 += __expf(s4.x);
        l1 += __expf(s4.y);
        l2 += __expf(s4.z);
        l3 += __expf(s4.w);
    }
    l0 += __shfl_xor(l0, 16); l0 += __shfl_xor(l0, 32);
    l1 += __shfl_xor(l1, 16); l1 += __shfl_xor(l1, 32);
    l2 += __shfl_xor(l2, 16); l2 += __shfl_xor(l2, 32);
    l3 += __shfl_xor(l3, 16); l3 += __shfl_xor(l3, 32);
    if (lg == 0) {
        redl[wv * 64 + p4 + 0] = l0;
        redl[wv * 64 + p4 + 1] = l1;
        redl[wv * 64 + p4 + 2] = l2;
        redl[wv * 64 + p4 + 3] = l3;
    }
    __syncthreads();
    if (tid < 64) {
        float L = redl[tid] + redl[64 + tid] + redl[128 + tid] + redl[192 + tid];
        pl[(b * QCH + q) * 64 + tid] = L;
    }
    // ---- phase 2: D_block = sum_{p,d in chunk} st[d][p] * ts[e_p][d]
    int d = tid & 127, ph2 = tid >> 7;        // 2 threads per d, split p-range
    const float* tsq = ts + (size_t)q * 128 + d;
    float D = 0.f;
#pragma unroll 8
    for (int i = 0; i < 32; ++i) {
        int p = ph2 * 32 + i;                 // wave-uniform p
        float sv = st[d * 65 + p];            // banks (d+p)%32: 2-way, free
        float tv = tsq[etab[p]];              // lanes span d: 256B coalesced
        D = fmaf(sv, tv, D);
    }
#pragma unroll
    for (int off = 1; off < 64; off <<= 1) D += __shfl_xor(D, off);
    if (lane == 0) rd[wv] = D;
    __syncthreads();
    if (tid == 0) pd[b * QCH + q] = rd[0] + rd[1] + rd[2] + rd[3];
}

// ---------------- K4: merge partials, final loss ----------------------------
__global__ __launch_bounds__(64) void k_final(const float* __restrict__ pl,
                                              const float* __restrict__ pd,
                                              const int* __restrict__ enc,
                                              const float* __restrict__ tsum,
                                              const float* __restrict__ tlogt,
                                              float* __restrict__ out) {
    int b = blockIdx.x, p = threadIdx.x;
    int base = b * QCH * 64 + p;
    float L = 0.f;
#pragma unroll
    for (int qq = 0; qq < QCH; ++qq) L += pl[base + qq * 64];
    float lse = logf(L);
    int e = enc[b * 64 + p];
    float row = tlogt[e] + tsum[e] * lse;
    if (p < QCH) row -= pd[b * QCH + p];      // sum_p of these = D_batch
    for (int off = 32; off; off >>= 1) row += __shfl_down(row, off);
    if (p == 0) atomicAdd(out, row * (1.f / 8192.f));
}

extern "C" void kernel_launch(void* const* d_in, const int* in_sizes, int n_in,
                              void* d_out, int out_size, void* d_ws, size_t ws_size,
                              hipStream_t stream) {
    const float* feat   = (const float*)d_in[0];
    const float* scores = (const float*)d_in[1];
    const int*   labels = (const int*)d_in[2];
    const float* ldaw   = (const float*)d_in[3];
    const float* ldab   = (const float*)d_in[4];
    const float* cc     = (const float*)d_in[5];
    const float* ts     = (const float*)d_in[6];
    float* out = (float*)d_out;
    float* ws  = (float*)d_ws;

    float* ft    = ws + FT_OFF;
    int*   enc   = (int*)(ws + ENC_OFF);
    float* tsum  = ws + TSUM_OFF;
    float* tlogt = ws + TLOGT_OFF;
    float* pl    = ws + PL_OFF;
    float* pd    = ws + PD_OFF;

    k_lda  <<<512,           256, 0, stream>>>(feat, ldaw, ldab, ft, out);
    k_enc  <<<BB * 2,        256, 0, stream>>>(ft, cc, labels, enc);
    k_main <<<BB * QCH + EMB, 256, 0, stream>>>(scores, ts, enc, labels, pl, pd, tsum, tlogt);
    k_final<<<BB,             64, 0, stream>>>(pl, pd, enc, tsum, tlogt, out);
}

// Round 5
// 279.176 us; speedup vs baseline: 1.9169x; 1.0119x over previous
//
#include <hip/hip_runtime.h>
#include <math.h>

#define BB 128
#define CIN 512
#define HW 64
#define OUTC 256
#define EMB 4096
#define DDIM 4096
#define ES 32
#define QCH 32          // D-chunks in k_main (128 d each, processed as 2x64)

// workspace layout (float offsets)
#define ENC_OFF   0          // 8192 ints
#define TSUM_OFF  8192       // 4096
#define TLOGT_OFF 12288      // 4096
#define PL_OFF    16384      // 128*32*64 = 262144
#define PD_OFF    278528     // 128*32 = 4096
#define FT_OFF    1048576    // 8192*256 floats

typedef short short8 __attribute__((ext_vector_type(8)));
typedef float floatx4 __attribute__((ext_vector_type(4)));

__device__ __forceinline__ unsigned short f2bf(float f) {
    unsigned int u = __builtin_bit_cast(unsigned int, f);
    u += 0x7FFFu + ((u >> 16) & 1u);          // RNE; inputs are finite
    return (unsigned short)(u >> 16);
}

// ---------------- K1: pure LDA, 512 blocks (~7us) ---------------------------
// R3 lesson: NO device fences / cross-block merges. Dependent reductions get
// their own launches.
__global__ __launch_bounds__(256) void k_lda(const float* __restrict__ feat,
                                             const float* __restrict__ w,
                                             const float* __restrict__ bias,
                                             float* __restrict__ ft,
                                             float* __restrict__ out) {
    __shared__ unsigned short As[64 * 40];    // staging, row stride 40
    int bx = blockIdx.x;
    int tid = threadIdx.x;
    if (bx == 0 && tid == 0) *out = 0.f;      // zero loss accumulator
    int nb = bx >> 2, ob = bx & 3;
    int n0 = nb * 64, o0 = ob * 64;
    int lane = tid & 63, wid = tid >> 6;
    int m = lane & 15, q = lane >> 4;
    int cc = tid >> 4;                        // staging: channels c and c+16
    int p4 = (tid & 15) * 4;                  // staging: 4 consecutive pixels
    const float* fbase = feat + (size_t)nb * CIN * HW;
    const float* wrow  = w + (size_t)(o0 + wid * 16 + m) * CIN;
    floatx4 acc[4] = {};
    for (int kt = 0; kt < 16; ++kt) {
        int k0 = kt * 32;
        float4 v0 = *(const float4*)(fbase + (size_t)(k0 + cc) * HW + p4);
        float4 v1 = *(const float4*)(fbase + (size_t)(k0 + cc + 16) * HW + p4);
        float4 w0 = *(const float4*)(wrow + k0 + 4 * q);
        float4 w1 = *(const float4*)(wrow + k0 + 16 + 4 * q);
        short8 bf;
        bf[0] = (short)f2bf(w0.x); bf[1] = (short)f2bf(w1.x);
        bf[2] = (short)f2bf(w0.y); bf[3] = (short)f2bf(w1.y);
        bf[4] = (short)f2bf(w0.z); bf[5] = (short)f2bf(w1.z);
        bf[6] = (short)f2bf(w0.w); bf[7] = (short)f2bf(w1.w);
        ushort2 pk;
        pk.x = f2bf(v0.x); pk.y = f2bf(v1.x);
        *(ushort2*)&As[(p4 + 0) * 40 + 2 * cc] = pk;
        pk.x = f2bf(v0.y); pk.y = f2bf(v1.y);
        *(ushort2*)&As[(p4 + 1) * 40 + 2 * cc] = pk;
        pk.x = f2bf(v0.z); pk.y = f2bf(v1.z);
        *(ushort2*)&As[(p4 + 2) * 40 + 2 * cc] = pk;
        pk.x = f2bf(v0.w); pk.y = f2bf(v1.w);
        *(ushort2*)&As[(p4 + 3) * 40 + 2 * cc] = pk;
        __syncthreads();
#pragma unroll
        for (int mt = 0; mt < 4; ++mt) {
            short8 af = *(short8*)&As[(mt * 16 + m) * 40 + q * 8];
            acc[mt] = __builtin_amdgcn_mfma_f32_16x16x32_bf16(af, bf, acc[mt], 0, 0, 0);
        }
        __syncthreads();
    }
    float bv = bias[o0 + wid * 16 + m];
#pragma unroll
    for (int mt = 0; mt < 4; ++mt)
#pragma unroll
        for (int rr = 0; rr < 4; ++rr) {
            int p = mt * 16 + q * 4 + rr;     // C/D: row = quad*4+reg, col = lane&15
            ft[(size_t)(n0 + p) * OUTC + o0 + wid * 16 + m] = acc[mt][rr] + bv;
        }
}

// ---------------- K2: enc = cls*32 + argmin_j ||ft_n - c_j||^2 --------------
// 256 blocks (b, pixel-half); centers async-staged via global_load_lds;
// 8 groups x 4 centers; double-buffered x row. Unchanged (verified).
__global__ __launch_bounds__(256) void k_enc(const float* __restrict__ ft,
                                             const float* __restrict__ cc,
                                             const int* __restrict__ labels,
                                             int* __restrict__ enc) {
    __shared__ __align__(16) float cbuf[ES * OUTC];   // 32 KB
    __shared__ float vred[8 * 32];
    __shared__ int   ired[8 * 32];
    int bx = blockIdx.x;
    int b = bx >> 1, ph = bx & 1;
    int tid = threadIdx.x;
    int lane = tid & 63, wid = tid >> 6;
    int cls = labels[b];
    const float* cbase = cc + (size_t)cls * ES * OUTC;
#pragma unroll
    for (int it = 0; it < 8; ++it) {
        int ch = wid * 8 + it;                // wave-uniform row; HW adds lane*16B
        __builtin_amdgcn_global_load_lds(
            (const __attribute__((address_space(1))) void*)(cbase + ch * OUTC + lane * 4),
            (__attribute__((address_space(3))) void*)&cbuf[ch * OUTC],
            16, 0, 0);
    }
    int p = tid & 31, jg = tid >> 5;          // 8 groups x 4 centers
    const float* xrow = ft + (size_t)(b * 64 + ph * 32 + p) * OUTC;
    float4 xa = *(const float4*)&xrow[0];
    float4 xb = *(const float4*)&xrow[4];
    float4 xc = *(const float4*)&xrow[8];
    float4 xd = *(const float4*)&xrow[12];
    __syncthreads();                          // drains global_load_lds (vmcnt)
    float sc[4] = {0.f, 0.f, 0.f, 0.f};
    for (int o = 0; o < OUTC; o += 16) {
        int on = (o + 16) & (OUTC - 1);       // wrap: last prefetch harmless
        float4 na = *(const float4*)&xrow[on + 0];
        float4 nb = *(const float4*)&xrow[on + 4];
        float4 nc = *(const float4*)&xrow[on + 8];
        float4 nd = *(const float4*)&xrow[on + 12];
        float ma0 = -2.f * xa.x, ma1 = -2.f * xa.y, ma2 = -2.f * xa.z, ma3 = -2.f * xa.w;
        float mb0 = -2.f * xb.x, mb1 = -2.f * xb.y, mb2 = -2.f * xb.z, mb3 = -2.f * xb.w;
        float mc0 = -2.f * xc.x, mc1 = -2.f * xc.y, mc2 = -2.f * xc.z, mc3 = -2.f * xc.w;
        float md0 = -2.f * xd.x, md1 = -2.f * xd.y, md2 = -2.f * xd.z, md3 = -2.f * xd.w;
#pragma unroll
        for (int jj = 0; jj < 4; ++jj) {
            const float* crow = &cbuf[(jg * 4 + jj) * OUTC + o];
            float4 c0 = *(const float4*)&crow[0];
            float4 c1 = *(const float4*)&crow[4];
            float4 c2 = *(const float4*)&crow[8];
            float4 c3 = *(const float4*)&crow[12];
            float s = sc[jj];
            s = fmaf(c0.x, c0.x + ma0, s);
            s = fmaf(c0.y, c0.y + ma1, s);
            s = fmaf(c0.z, c0.z + ma2, s);
            s = fmaf(c0.w, c0.w + ma3, s);
            s = fmaf(c1.x, c1.x + mb0, s);
            s = fmaf(c1.y, c1.y + mb1, s);
            s = fmaf(c1.z, c1.z + mb2, s);
            s = fmaf(c1.w, c1.w + mb3, s);
            s = fmaf(c2.x, c2.x + mc0, s);
            s = fmaf(c2.y, c2.y + mc1, s);
            s = fmaf(c2.z, c2.z + mc2, s);
            s = fmaf(c2.w, c2.w + mc3, s);
            s = fmaf(c3.x, c3.x + md0, s);
            s = fmaf(c3.y, c3.y + md1, s);
            s = fmaf(c3.z, c3.z + md2, s);
            s = fmaf(c3.w, c3.w + md3, s);
            sc[jj] = s;
        }
        xa = na; xb = nb; xc = nc; xd = nd;
    }
    float best = sc[0]; int bj = jg * 4;
#pragma unroll
    for (int jj = 1; jj < 4; ++jj)
        if (sc[jj] < best) { best = sc[jj]; bj = jg * 4 + jj; }
    vred[jg * 32 + p] = best;
    ired[jg * 32 + p] = bj;
    __syncthreads();
    if (tid < 32) {
        float bv = vred[tid]; int bi = ired[tid];
#pragma unroll
        for (int g = 1; g < 8; ++g) {
            float v = vred[g * 32 + tid];
            if (v < bv) { bv = v; bi = ired[g * 32 + tid]; }
        }
        enc[b * 64 + ph * 32 + tid] = cls * ES + bi;
    }
}

// ---------------- K3: main stream (blocks 0..4095)  ||  rowsum (4096..8191) -
// R4 post-mortem: 33KB st tile -> 4 blocks/CU = 50% wave occupancy; phase 2
// (latency-chain of L2 gathers) under-hidden. Split the 128-d chunk into
// 2x64-d sub-tiles: LDS ~18KB -> 8 blocks/CU = 32 waves/CU, same traffic,
// same bank-free patterns, twice the latency-hiding.
__global__ __launch_bounds__(256) void k_main(const float* __restrict__ scores,
                                              const float* __restrict__ ts,
                                              const int* __restrict__ enc,
                                              const int* __restrict__ labels,
                                              float* __restrict__ pl,
                                              float* __restrict__ pd,
                                              float* __restrict__ tsum,
                                              float* __restrict__ tlogt) {
    __shared__ float st[64 * 65];             // [d][p], pad 65 -> bank (d+p)%32
    __shared__ float redl[4 * 64];
    __shared__ int   etab[64];
    __shared__ float rd[4];
    __shared__ int present;
    __shared__ float r8[8];
    int bx = blockIdx.x;
    int tid = threadIdx.x;
    if (bx >= BB * QCH) {
        // ---------------- rowsum role ----------------
        int e = bx - BB * QCH;
        if (tid == 0) present = 0;
        __syncthreads();
        int cls = e >> 5;
        if (tid < BB && labels[tid] == cls) present = 1;
        __syncthreads();
        if (!present) return;
        const float* row = ts + (size_t)e * DDIM;
        float st_ = 0.f, sl = 0.f;
#pragma unroll
        for (int i = 0; i < 4; ++i) {
            float4 t4 = *(const float4*)&row[tid * 4 + i * 1024];
            float tv[4] = {t4.x, t4.y, t4.z, t4.w};
#pragma unroll
            for (int j = 0; j < 4; ++j) {
                float t = tv[j];
                st_ += t;
                sl += (t > 0.f) ? t * logf(t) : 0.f;
            }
        }
        for (int off = 32; off; off >>= 1) {
            st_ += __shfl_down(st_, off);
            sl += __shfl_down(sl, off);
        }
        int lane = tid & 63, wv = tid >> 6;
        if (lane == 0) { r8[wv] = st_; r8[4 + wv] = sl; }
        __syncthreads();
        if (tid == 0) {
            tsum[e]  = r8[0] + r8[1] + r8[2] + r8[3];
            tlogt[e] = r8[4] + r8[5] + r8[6] + r8[7];
        }
        return;
    }
    // ---------------- main role ----------------
    int b = bx >> 5, q = bx & 31;
    int lane = tid & 63, wv = tid >> 6;
    int pg = lane & 15, lg = lane >> 4;
    if (tid < 64) etab[tid] = enc[b * 64 + tid] * DDIM;
    int p4 = pg * 4;
    int dl = wv * 4 + lg;                     // local d in [0,16), +16*it
    float l0 = 0.f, l1 = 0.f, l2 = 0.f, l3 = 0.f;
    float D = 0.f;
    int d2 = lane;                            // phase-2: lanes span 64 d's
    int pb = wv * 16;                         // phase-2: wave's 16-pixel range
#pragma unroll
    for (int h = 0; h < 2; ++h) {
        const float* sptr = scores + (size_t)b * DDIM * HW
                          + (size_t)(q * 128 + h * 64 + dl) * HW + p4;
        // ---- phase 1: stream 64 d's, stage transposed, accumulate sumexp
#pragma unroll
        for (int it = 0; it < 4; ++it) {
            float4 s4 = *(const float4*)(sptr + (size_t)(it * 16) * HW);
            float* sw = &st[(dl + it * 16) * 65 + p4];   // banks (d+p)%32: free
            sw[0] = s4.x; sw[1] = s4.y; sw[2] = s4.z; sw[3] = s4.w;
            l0 += __expf(s4.x);
            l1 += __expf(s4.y);
            l2 += __expf(s4.z);
            l3 += __expf(s4.w);
        }
        __syncthreads();                      // tile ready (also covers etab, h=0)
        // ---- phase 2: D += sum_{p in range, d in sub-tile} st[d][p]*ts[e_p][d]
        const float* tsq = ts + (size_t)q * 128 + h * 64 + d2;
#pragma unroll 8
        for (int i = 0; i < 16; ++i) {
            int p = pb + i;                   // wave-uniform p
            float sv = st[d2 * 65 + p];       // banks (d2+p)%32: 2-way, free
            float tv = tsq[etab[p]];          // lanes span d: 256B coalesced
            D = fmaf(sv, tv, D);
        }
        __syncthreads();                      // before overwriting st (h=1)
    }
    l0 += __shfl_xor(l0, 16); l0 += __shfl_xor(l0, 32);
    l1 += __shfl_xor(l1, 16); l1 += __shfl_xor(l1, 32);
    l2 += __shfl_xor(l2, 16); l2 += __shfl_xor(l2, 32);
    l3 += __shfl_xor(l3, 16); l3 += __shfl_xor(l3, 32);
    if (lg == 0) {
        redl[wv * 64 + p4 + 0] = l0;
        redl[wv * 64 + p4 + 1] = l1;
        redl[wv * 64 + p4 + 2] = l2;
        redl[wv * 64 + p4 + 3] = l3;
    }
#pragma unroll
    for (int off = 1; off < 64; off <<= 1) D += __shfl_xor(D, off);
    if (lane == 0) rd[wv] = D;
    __syncthreads();
    if (tid < 64) {
        float L = redl[tid] + redl[64 + tid] + redl[128 + tid] + redl[192 + tid];
        pl[(b * QCH + q) * 64 + tid] = L;
    }
    if (tid == 0) pd[b * QCH + q] = rd[0] + rd[1] + rd[2] + rd[3];
}

// ---------------- K4: merge partials, final loss (256 threads) --------------
__global__ __launch_bounds__(256) void k_final(const float* __restrict__ pl,
                                               const float* __restrict__ pd,
                                               const int* __restrict__ enc,
                                               const float* __restrict__ tsum,
                                               const float* __restrict__ tlogt,
                                               float* __restrict__ out) {
    __shared__ float redL[4 * 64];
    int b = blockIdx.x, tid = threadIdx.x;
    int p = tid & 63, qg = tid >> 6;          // 4 q-groups x 8 q each
    float L = 0.f;
#pragma unroll
    for (int qq = qg * 8; qq < qg * 8 + 8; ++qq)
        L += pl[(b * QCH + qq) * 64 + p];     // lanes span p: coalesced
    redL[qg * 64 + p] = L;
    __syncthreads();
    if (tid < 64) {
        float Lt = redL[tid] + redL[64 + tid] + redL[128 + tid] + redL[192 + tid];
        float lse = logf(Lt);
        int e = enc[b * 64 + tid];
        float row = tlogt[e] + tsum[e] * lse;
        if (tid < QCH) row -= pd[b * QCH + tid];   // sum_p of these = D_batch
        for (int off = 32; off; off >>= 1) row += __shfl_down(row, off);
        if (tid == 0) atomicAdd(out, row * (1.f / 8192.f));
    }
}

extern "C" void kernel_launch(void* const* d_in, const int* in_sizes, int n_in,
                              void* d_out, int out_size, void* d_ws, size_t ws_size,
                              hipStream_t stream) {
    const float* feat   = (const float*)d_in[0];
    const float* scores = (const float*)d_in[1];
    const int*   labels = (const int*)d_in[2];
    const float* ldaw   = (const float*)d_in[3];
    const float* ldab   = (const float*)d_in[4];
    const float* cc     = (const float*)d_in[5];
    const float* ts     = (const float*)d_in[6];
    float* out = (float*)d_out;
    float* ws  = (float*)d_ws;

    float* ft    = ws + FT_OFF;
    int*   enc   = (int*)(ws + ENC_OFF);
    float* tsum  = ws + TSUM_OFF;
    float* tlogt = ws + TLOGT_OFF;
    float* pl    = ws + PL_OFF;
    float* pd    = ws + PD_OFF;

    k_lda  <<<512,            256, 0, stream>>>(feat, ldaw, ldab, ft, out);
    k_enc  <<<BB * 2,         256, 0, stream>>>(ft, cc, labels, enc);
    k_main <<<BB * QCH + EMB, 256, 0, stream>>>(scores, ts, enc, labels, pl, pd, tsum, tlogt);
    k_final<<<BB,             256, 0, stream>>>(pl, pd, enc, tsum, tlogt, out);
}